// Round 8
// baseline (94.925 us; speedup 1.0000x reference)
//
#include <hip/hip_runtime.h>
#include <hip/hip_fp16.h>

#define N 2048
#define ONW 4096
#define TW 128                        // tile width (pixels)
#define TH 32                         // tile height (pixels)
#define HW 132                        // halo tile width (ints)
#define HH 36                         // halo tile height
#define HELEMS (HW * HH)              // 4752
#define LUT_ENTRIES 12288
#define LUT_BYTES (LUT_ENTRIES * 8)   // 98304
#define SMEM_BYTES (LUT_BYTES + 2 * HELEMS * 4)  // 136320 <= 160K

typedef _Float16 half4v __attribute__((ext_vector_type(4)));
typedef float fvec4 __attribute__((ext_vector_type(4)));

__device__ __forceinline__ int reflect(int i) {
    i = i < 0 ? -i : i;
    return i >= N ? 2 * N - 2 - i : i;
}

// async DMA staging of one 36x132 halo tile: no VGPR round-trip, no ds_write.
// LDS dest is wave-uniform base + lane*4 (m104/m108 semantics); e = tid + u*1024
// is lane-contiguous per (ty,u), so the layout matches exactly.
__device__ __forceinline__ void stage_tile_async(
    const int* __restrict__ img, int* lds_buf, int x0, int yb, int ty, int tx)
{
    #pragma unroll
    for (int u = 0; u < 5; ++u) {
        const int ebase = ty * 64 + u * 1024;     // wave-uniform
        const int e = ebase + tx;
        if (e < HELEMS) {
            const int rr = e / HW, cc = e - rr * HW;
            const int* src = img + reflect(yb + rr - 2) * N + reflect(x0 + cc - 2);
            __builtin_amdgcn_global_load_lds(
                (const __attribute__((address_space(1))) void*)src,
                (__attribute__((address_space(3))) void*)(lds_buf + ebase),
                4, 0, 0);
        }
    }
}

__global__ __launch_bounds__(1024, 4) void hdblut_kernel(
    const int* __restrict__ img, const float4* __restrict__ w4,
    float* __restrict__ out)
{
    extern __shared__ unsigned char smem[];
    half4v* lut = (half4v*)smem;
    int* bufs = (int*)(smem + LUT_BYTES);

    const int tx = threadIdx.x;            // 0..63  (one wave = one ty row)
    const int ty = threadIdx.y;            // 0..15
    const int tid = ty * 64 + tx;
    const int x0 = (int)(blockIdx.x & 15) * TW;        // 16 x-strips
    const int y0 = (int)(blockIdx.x >> 4) * (TH * 4);  // 16 y-bands, 4 tiles each

    // tile 0 staging via async DMA (overlaps the LUT convert below)
    stage_tile_async(img, bufs, x0, y0, ty, tx);

    // fp32 -> fp16 LUT into LDS (once per block)
    #pragma unroll
    for (int i = 0; i < 12; ++i) {
        int j = tid + i * 1024;
        float4 v = w4[j];
        half4v h;
        h.x = (_Float16)v.x; h.y = (_Float16)v.y;
        h.z = (_Float16)v.z; h.w = (_Float16)v.w;
        lut[j] = h;
    }
    __syncthreads();   // drains DMA (vmcnt) + LUT writes

    const int bo[3][2] = {{0, 1}, {1, 1}, {1, 2}};
    const int co[3][2] = {{0, 2}, {2, 2}, {2, 1}};
    const float s = 1.0f / 3.0f;
    fvec4* o4 = (fvec4*)out;

    #pragma unroll 1
    for (int t = 0; t < 4; ++t) {
        int* cur = bufs + (t & 1) * HELEMS;
        int* nxt = bufs + ((t + 1) & 1) * HELEMS;

        // async-stage next tile; completes by the barrier at loop end
        if (t < 3)
            stage_tile_async(img, nxt, x0, y0 + (t + 1) * TH, ty, tx);

        // 6x6 neighborhood for this thread's 2x2 pixel patch
        int n[6][6];
        {
            const int r0 = 2 * ty, c0 = 2 * tx;
            #pragma unroll
            for (int r = 0; r < 6; ++r)
                #pragma unroll
                for (int j = 0; j < 3; ++j) {
                    int2 t2 = *(const int2*)&cur[(r0 + r) * HW + c0 + 2 * j];
                    n[r][2 * j] = t2.x; n[r][2 * j + 1] = t2.y;
                }
        }

        float acc[2][2][4];
        #pragma unroll
        for (int i = 0; i < 2; ++i)
            #pragma unroll
            for (int j = 0; j < 2; ++j)
                #pragma unroll
                for (int c = 0; c < 4; ++c) acc[i][j][c] = 0.f;

        // compute all 48 indices (both pixel-pairs)
        int idx[2][24];
        #pragma unroll
        for (int pi = 0; pi < 2; ++pi) {
            #pragma unroll
            for (int pj = 0; pj < 2; ++pj) {
                const int a8 = n[2 + pi][2 + pj] << 8;
                #pragma unroll
                for (int r = 0; r < 4; ++r) {
                    #pragma unroll
                    for (int k = 0; k < 3; ++k) {
                        const int bp = bo[k][0], bq = bo[k][1];
                        const int cp = co[k][0], cq = co[k][1];
                        const int bdi = (r == 0) ? bp : (r == 1) ? bq : (r == 2) ? -bp : -bq;
                        const int bdj = (r == 0) ? bq : (r == 1) ? -bp : (r == 2) ? -bq : bp;
                        const int cdi = (r == 0) ? cp : (r == 1) ? cq : (r == 2) ? -cp : -cq;
                        const int cdj = (r == 0) ? cq : (r == 1) ? -cp : (r == 2) ? -cq : cp;
                        const int bv = n[pi + 2 + bdi][pj + 2 + bdj];
                        const int cv = n[pi + 2 + cdi][pj + 2 + cdj];
                        idx[pi][pj * 12 + r * 3 + k] = (k * 4096 + a8) + (bv * 16 + cv);
                    }
                }
            }
        }

        // 48 gathers in flight before first consume (two pinned 24-groups)
        half4v vA[24], vB[24];
        #pragma unroll
        for (int i = 0; i < 24; ++i) vA[i] = lut[idx[0][i]];
        __builtin_amdgcn_sched_group_barrier(0x100, 24, 0);
        #pragma unroll
        for (int i = 0; i < 24; ++i) vB[i] = lut[idx[1][i]];
        __builtin_amdgcn_sched_group_barrier(0x100, 24, 0);

        #pragma unroll
        for (int pi = 0; pi < 2; ++pi) {
            half4v* v = (pi == 0) ? vA : vB;
            #pragma unroll
            for (int pj = 0; pj < 2; ++pj) {
                float* o = acc[pi][pj];
                #pragma unroll
                for (int r = 0; r < 4; ++r) {
                    half4v S = v[pj * 12 + 3 * r] + v[pj * 12 + 3 * r + 1]
                                                  + v[pj * 12 + 3 * r + 2];
                    const float x = (float)S.x, y = (float)S.y;
                    const float z = (float)S.z, w = (float)S.w;
                    if (r == 0)      { o[0] += x; o[1] += y; o[2] += z; o[3] += w; }
                    else if (r == 1) { o[0] += z; o[1] += x; o[2] += w; o[3] += y; }
                    else if (r == 2) { o[0] += w; o[1] += z; o[2] += y; o[3] += x; }
                    else             { o[0] += y; o[1] += w; o[2] += x; o[3] += z; }
                }
            }
        }

        // wave-contiguous stores (1 KiB per wave per row)
        const int py = y0 + t * TH + 2 * ty;
        const int ox = (x0 + 2 * tx) * 2;
        {
            fvec4 v0 = {acc[0][0][0] * s, acc[0][0][1] * s, acc[0][1][0] * s, acc[0][1][1] * s};
            fvec4 v1 = {acc[0][0][2] * s, acc[0][0][3] * s, acc[0][1][2] * s, acc[0][1][3] * s};
            fvec4 v2 = {acc[1][0][0] * s, acc[1][0][1] * s, acc[1][1][0] * s, acc[1][1][1] * s};
            fvec4 v3 = {acc[1][0][2] * s, acc[1][0][3] * s, acc[1][1][2] * s, acc[1][1][3] * s};
            o4[((2 * py + 0) * ONW + ox) >> 2] = v0;
            o4[((2 * py + 1) * ONW + ox) >> 2] = v1;
            o4[((2 * py + 2) * ONW + ox) >> 2] = v2;
            o4[((2 * py + 3) * ONW + ox) >> 2] = v3;
        }

        __syncthreads();   // drains DMA into nxt + orders buffer swap
    }
}

extern "C" void kernel_launch(void* const* d_in, const int* in_sizes, int n_in,
                              void* d_out, int out_size, void* d_ws, size_t ws_size,
                              hipStream_t stream)
{
    const int* img = (const int*)d_in[0];
    const float4* w4 = (const float4*)d_in[1];
    float* out = (float*)d_out;
    (void)hipFuncSetAttribute(reinterpret_cast<const void*>(hdblut_kernel),
                              hipFuncAttributeMaxDynamicSharedMemorySize, SMEM_BYTES);
    hdblut_kernel<<<dim3(256), dim3(64, 16), SMEM_BYTES, stream>>>(img, w4, out);
}